// Round 8
// baseline (181.078 us; speedup 1.0000x reference)
//
#include <hip/hip_runtime.h>
#include <hip/hip_bf16.h>
#include <math.h>

#define NPTS   16384
#define NCH    8
#define MT     64
#define LSTR   264   // act row stride (ushort): 33 x 16B -> bank-balanced b128 reads
#define SEG    16384 // fixed bucket segment per chart
#define CPAD   64    // cursor padding (ints) -> 256 B between atomics

typedef short bf16x8 __attribute__((ext_vector_type(8)));
typedef float f32x4  __attribute__((ext_vector_type(4)));

__device__ __forceinline__ float bf2f(unsigned short u){
  union { unsigned int i; float f; } v; v.i = ((unsigned int)u) << 16; return v.f;
}
__device__ __forceinline__ unsigned short f2bf(float f){
  union { float f; unsigned int i; } v; v.f = f;
  unsigned int x = v.i;
  return (unsigned short)((x + 0x7fffu + ((x >> 16) & 1u)) >> 16); // RNE
}
__device__ __forceinline__ void dma16(const void* g, void* l){
  __builtin_amdgcn_global_load_lds(
      (const __attribute__((address_space(1))) unsigned int*)g,
      (__attribute__((address_space(3))) unsigned int*)l, 16, 0, 0);
}

// ---- prep: transpose to k8-major + bucketing ------------------------------
// Wth[c][l] slot-major: slot = k8*256 + n (k8 = k/8, 0..31); each slot = 8 bf16
//   (k = k8*8+j). Blocks 0..191: (mat = bid>>2, ck = bid&3), 64 k-rows each.
// Wt0[c]: slot = k8*256 + n, k8 0..3 (k padded 29->32). Blocks 192..199.
// Blocks 200..207: scatter 2048 points each, two-phase LDS count, 8 atomics/blk.

__global__ __launch_bounds__(256) void prep_k(
    const float* __restrict__ Wh, const float* __restrict__ W0,
    const int* __restrict__ midx,
    unsigned short* __restrict__ Wth, unsigned short* __restrict__ Wt0,
    int* __restrict__ cursors, int* __restrict__ bucket){
  int bid = blockIdx.x, tid = threadIdx.x;
  if (bid < 192){
    __shared__ __align__(16) unsigned short tile[64 * LSTR];
    int mat = bid >> 2, ck = bid & 3;
    const float* src = Wh + (size_t)mat * 65536 + (size_t)ck * 64 * 256;
    // load 64 k-rows x 256 n, convert to bf16 into LDS
    int r = tid >> 2, seg = (tid & 3) * 64;
    const float* sp = &src[r * 256 + seg];
    #pragma unroll
    for (int j8 = 0; j8 < 8; j8++){
      float4 f0 = *(const float4*)&sp[j8 * 8];
      float4 f1 = *(const float4*)&sp[j8 * 8 + 4];
      __align__(16) unsigned short t8[8];
      t8[0]=f2bf(f0.x); t8[1]=f2bf(f0.y); t8[2]=f2bf(f0.z); t8[3]=f2bf(f0.w);
      t8[4]=f2bf(f1.x); t8[5]=f2bf(f1.y); t8[6]=f2bf(f1.z); t8[7]=f2bf(f1.w);
      *(uint4*)&tile[r * LSTR + seg + j8 * 8] = *(const uint4*)t8;
    }
    __syncthreads();
    // emit 2048 slots of 16B: slot s -> k8l = s>>8 (0..7), n = s&255
    unsigned short* dst = Wth + (size_t)mat * 65536 + (size_t)ck * 16384;
    #pragma unroll
    for (int it = 0; it < 8; it++){
      int s = it * 256 + tid;
      int k8l = s >> 8, n = s & 255;
      __align__(16) unsigned short t8[8];
      #pragma unroll
      for (int j = 0; j < 8; j++) t8[j] = tile[(k8l * 8 + j) * LSTR + n];
      *(uint4*)&dst[(size_t)s * 8] = *(const uint4*)t8;
    }
  } else if (bid < 200){
    int c = bid - 192;
    #pragma unroll
    for (int it = 0; it < 4; it++){
      int s = it * 256 + tid;
      int k8 = s >> 8, n = s & 255;
      __align__(16) unsigned short t8[8];
      #pragma unroll
      for (int j = 0; j < 8; j++){
        int k = k8 * 8 + j;
        t8[j] = (k < 29) ? f2bf(W0[(c * 29 + k) * 256 + n]) : (unsigned short)0;
      }
      *(uint4*)&Wt0[(size_t)c * 8192 + (size_t)s * 8] = *(const uint4*)t8;
    }
  } else {
    __shared__ int h[NCH], cur[NCH];
    int seg = bid - 200;
    int lane = tid & 63;
    if (tid < NCH) h[tid] = 0;
    __syncthreads();
    for (int it = 0; it < 8; it++){
      int i = seg * 2048 + it * 256 + tid;
      int c = midx[i];
      #pragma unroll
      for (int cc = 0; cc < NCH; cc++){
        unsigned long long m = __ballot(c == cc);
        if (m && lane == (int)(__ffsll((long long)m) - 1))
          atomicAdd(&h[cc], (int)__popcll(m));
      }
    }
    __syncthreads();
    if (tid < NCH) cur[tid] = atomicAdd(&cursors[tid * CPAD], h[tid]);
    __syncthreads();
    for (int it = 0; it < 8; it++){
      int i = seg * 2048 + it * 256 + tid;
      int c = midx[i];
      #pragma unroll
      for (int cc = 0; cc < NCH; cc++){
        unsigned long long m = __ballot(c == cc);
        if (!m) continue;
        int leader = (int)(__ffsll((long long)m) - 1);
        int wb = 0;
        if (lane == leader) wb = atomicAdd(&cur[cc], (int)__popcll(m));
        wb = __shfl(wb, leader);
        if (c == cc){
          int rk = (int)__popcll(m & ((1ull << lane) - 1));
          bucket[cc * SEG + wb + rk] = i;
        }
      }
    }
  }
}

// ---- main fused MLP: N-split waves, K-split DMA chunks, m97 dbuf ----------

__global__ __launch_bounds__(256) void mlp_k(
    const float* __restrict__ x,
    const float* __restrict__ proc,
    const float* __restrict__ b0,
    const float* __restrict__ bh,
    const float* __restrict__ Wl,
    const float* __restrict__ bl,
    const unsigned short* __restrict__ Wt0,
    const unsigned short* __restrict__ Wth,
    const int* __restrict__ counts,
    const int* __restrict__ bucket,
    float* __restrict__ out)
{
  __shared__ __align__(16) unsigned short actA[MT * LSTR];
  __shared__ __align__(16) unsigned short actB[MT * LSTR];
  __shared__ __align__(16) unsigned short wbuf[2][16384];  // 2 x 32 KB
  __shared__ float biasb[7 * 256];
  __shared__ float wlb[512];
  __shared__ int ridx[MT];

  int chart = blockIdx.x & 7;     // XCD swizzle
  int tile  = blockIdx.x >> 3;
  int cnt   = counts[chart * CPAD] - tile * MT;
  if (cnt <= 0) return;
  if (cnt > MT) cnt = MT;

  int tid  = threadIdx.x;
  int lane = tid & 63;
  int wv   = tid >> 6;
  int l15  = lane & 15;
  int quad = lane >> 4;
  int cb   = wv * 64;             // this wave's col base (N-split)

  const unsigned short* Wc = Wth + ((size_t)(chart * 6) << 16);

  // DMA chunk (layer l in 1..6, ck in 0..3): slots [ck*2048, +2048), linear.
  #define ISSUE(l, ck, buf) do {                                              \
    const unsigned short* src_ = Wc + (((size_t)((l) - 1)) << 16)             \
                               + (((size_t)(ck)) << 14);                      \
    _Pragma("unroll")                                                         \
    for (int it = 0; it < 8; it++){                                           \
      int sb = (wv * 8 + it) * 64;                                            \
      dma16(src_ + (size_t)(sb + lane) * 8, &wbuf[buf][(size_t)sb * 8]);      \
    }                                                                         \
  } while (0)

  // prologue DMA: layer0 B (16 KB -> wbuf[0]) + layer1 chunk0 (-> wbuf[1])
  {
    const unsigned short* s0 = Wt0 + chart * 8192;
    #pragma unroll
    for (int it = 0; it < 4; it++){
      int sb = (wv * 4 + it) * 64;
      dma16(s0 + (size_t)(sb + lane) * 8, &wbuf[0][(size_t)sb * 8]);
    }
  }
  ISSUE(1, 0, 1);

  // stage biases + Wl
  biasb[tid] = b0[chart * 256 + tid];
  #pragma unroll
  for (int j = 0; j < 6; j++)
    biasb[(j + 1) * 256 + tid] = bh[(chart * 6 + j) * 256 + tid];
  wlb[tid]       = Wl[chart * 512 + tid];
  wlb[256 + tid] = Wl[chart * 512 + 256 + tid];

  // positional encoding -> actA rows [0..64) cols [0..32)
  if (tid < MT){
    int row = tid;
    int g = (row < cnt) ? bucket[chart * SEG + tile * MT + row] : -1;
    ridx[row] = g;
    unsigned short* rowp = &actA[row * LSTR];
    if (g >= 0){
      float xv0 = x[g*3+0], xv1 = x[g*3+1], xv2 = x[g*3+2];
      rowp[0] = f2bf(xv0); rowp[1] = f2bf(xv1); rowp[2] = f2bf(xv2);
      #pragma unroll
      for (int d = 1; d <= 4; d++){
        float s = (float)(1 << d) * 3.14159265358979323846f;
        int o = 3 + (d - 1) * 6;
        rowp[o+0] = f2bf(sinf(s*xv0)); rowp[o+1] = f2bf(sinf(s*xv1)); rowp[o+2] = f2bf(sinf(s*xv2));
        rowp[o+3] = f2bf(cosf(s*xv0)); rowp[o+4] = f2bf(cosf(s*xv1)); rowp[o+5] = f2bf(cosf(s*xv2));
      }
      rowp[27] = f2bf(proc[0]); rowp[28] = f2bf(proc[1]);
      rowp[29] = 0; rowp[30] = 0; rowp[31] = 0;
    } else {
      #pragma unroll
      for (int k = 0; k < 32; k++) rowp[k] = 0;
    }
  }
  __syncthreads();   // drains prologue DMA; publishes PE + biases

  f32x4 acc[4][4];
  const f32x4 zz = {0.f, 0.f, 0.f, 0.f};

  // Layer 0: (64x32)@(32x256); wave computes all 64 rows x its 64 cols
  {
    bf16x8 a0[4];
    #pragma unroll
    for (int mt = 0; mt < 4; mt++)
      a0[mt] = *(const bf16x8*)&actA[(mt * 16 + l15) * LSTR + quad * 8];
    #pragma unroll
    for (int nt = 0; nt < 4; nt++){
      int slot = quad * 256 + cb + nt * 16 + l15;
      bf16x8 b = *(const bf16x8*)&wbuf[0][slot * 8];
      #pragma unroll
      for (int mt = 0; mt < 4; mt++)
        acc[mt][nt] = __builtin_amdgcn_mfma_f32_16x16x32_bf16(a0[mt], b, zz, 0, 0, 0);
    }
    #pragma unroll
    for (int nt = 0; nt < 4; nt++){
      int col = cb + nt * 16 + l15;
      float bias = biasb[col];
      #pragma unroll
      for (int mt = 0; mt < 4; mt++)
        #pragma unroll
        for (int r = 0; r < 4; r++){
          float v = acc[mt][nt][r] + bias;
          v = v > 0.f ? v : 0.f;
          actB[(mt * 16 + quad * 4 + r) * LSTR + col] = f2bf(v);
        }
    }
  }

  // 24 chunks: layer l = 1+(lc>>2), k-range ck = lc&3; chunk lc lives in
  // wbuf[(lc+1)&1]; DMA for lc+1 issued after the barrier that frees its buffer.
  for (int lc = 0; lc < 24; lc++){
    int l = 1 + (lc >> 2), ck = lc & 3, buf = (lc + 1) & 1;
    __syncthreads();          // chunk lc DMA complete; buffer lc+1 free
    if (lc + 1 < 24){
      int lc2 = lc + 1;
      ISSUE(1 + (lc2 >> 2), lc2 & 3, lc & 1);
    }
    const unsigned short* ain = (l & 1) ? actB : actA;
    unsigned short* aout      = (l & 1) ? actA : actB;

    bf16x8 a[4][2];
    #pragma unroll
    for (int mt = 0; mt < 4; mt++)
      #pragma unroll
      for (int kl = 0; kl < 2; kl++)
        a[mt][kl] = *(const bf16x8*)&ain[(mt * 16 + l15) * LSTR + ck * 64 + kl * 32 + quad * 8];

    #pragma unroll
    for (int kl = 0; kl < 2; kl++)
      #pragma unroll
      for (int nt = 0; nt < 4; nt++){
        int slot = (kl * 4 + quad) * 256 + cb + nt * 16 + l15;
        bf16x8 b = *(const bf16x8*)&wbuf[buf][slot * 8];
        #pragma unroll
        for (int mt = 0; mt < 4; mt++){
          f32x4 cin = (ck == 0 && kl == 0) ? zz : acc[mt][nt];
          acc[mt][nt] = __builtin_amdgcn_mfma_f32_16x16x32_bf16(a[mt][kl], b, cin, 0, 0, 0);
        }
      }

    if (ck == 3){
      #pragma unroll
      for (int nt = 0; nt < 4; nt++){
        int col = cb + nt * 16 + l15;
        float bias = biasb[l * 256 + col];
        #pragma unroll
        for (int mt = 0; mt < 4; mt++)
          #pragma unroll
          for (int r = 0; r < 4; r++){
            float v = acc[mt][nt][r] + bias;
            v = v > 0.f ? v : 0.f;
            aout[(mt * 16 + quad * 4 + r) * LSTR + col] = f2bf(v);
          }
      }
    }
  }
  __syncthreads();   // layer-6 acts (actB) visible to all

  // Final layer: (64x256)@(256x2) + sigmoid
  {
    int m = tid >> 2;
    int p = tid & 3;
    const unsigned short* hrow = actB + m * LSTR + p * 64;
    const float* wlp = wlb + p * 128;
    float s0 = 0.f, s1 = 0.f;
    #pragma unroll 8
    for (int k = 0; k < 64; k += 2){
      float4 w4 = *(const float4*)&wlp[k * 2];
      unsigned int h2 = *(const unsigned int*)&hrow[k];
      float hv0 = bf2f((unsigned short)(h2 & 0xffff));
      float hv1 = bf2f((unsigned short)(h2 >> 16));
      s0 += hv0 * w4.x + hv1 * w4.z;
      s1 += hv0 * w4.y + hv1 * w4.w;
    }
    s0 += __shfl_xor(s0, 1); s0 += __shfl_xor(s0, 2);
    s1 += __shfl_xor(s1, 1); s1 += __shfl_xor(s1, 2);
    if (p == 0){
      int g = ridx[m];
      if (g >= 0){
        float o0 = 1.f / (1.f + __expf(-(s0 + bl[chart*2+0])));
        float o1 = 1.f / (1.f + __expf(-(s1 + bl[chart*2+1])));
        *(float2*)&out[(size_t)g * 2] = make_float2(o0, o1);
      }
    }
  }
}

// ---- launch ---------------------------------------------------------------

extern "C" void kernel_launch(void* const* d_in, const int* in_sizes, int n_in,
                              void* d_out, int out_size, void* d_ws, size_t ws_size,
                              hipStream_t stream){
  const float* x    = (const float*)d_in[0];
  const float* proc = (const float*)d_in[1];
  const float* W0   = (const float*)d_in[2];
  const float* b0   = (const float*)d_in[3];
  const float* Wh   = (const float*)d_in[4];
  const float* bh   = (const float*)d_in[5];
  const float* Wl   = (const float*)d_in[6];
  const float* bl   = (const float*)d_in[7];
  const int* midx = (const int*)d_in[8];
  float* out = (float*)d_out;

  char* ws = (char*)d_ws;
  int* cursors = (int*)ws;                          // NCH * CPAD ints (padded)
  int* bucket  = cursors + NCH * CPAD;              // NCH * SEG ints
  size_t off = (((size_t)(NCH * CPAD + NCH * SEG)) * 4 + 15) & ~(size_t)15;
  unsigned short* Wt0 = (unsigned short*)(ws + off);  // 8 * 8192 bf16
  unsigned short* Wth = Wt0 + NCH * 8192;             // 8 * 6 * 65536 bf16

  hipMemsetAsync(cursors, 0, NCH * CPAD * sizeof(int), stream);
  hipLaunchKernelGGL(prep_k, dim3(208),  dim3(256), 0, stream,
                     Wh, W0, midx, Wth, Wt0, cursors, bucket);
  hipLaunchKernelGGL(mlp_k,  dim3(2048), dim3(256), 0, stream,
                     x, proc, b0, bh, Wl, bl, Wt0, Wth, cursors, bucket, out);
}

// Round 10
// 128.401 us; speedup vs baseline: 1.4103x; 1.4103x over previous
//
#include <hip/hip_runtime.h>
#include <hip/hip_bf16.h>
#include <math.h>

#define NPTS   16384
#define NCH    8
#define MT     64
#define LSTR   264   // act row stride (ushort)
#define SEG    16384 // fixed bucket segment per chart
#define PSEG   2048  // points per scatter sub-segment

typedef short bf16x8 __attribute__((ext_vector_type(8)));
typedef float f32x4  __attribute__((ext_vector_type(4)));

__device__ __forceinline__ float bf2f(unsigned short u){
  union { unsigned int i; float f; } v; v.i = ((unsigned int)u) << 16; return v.f;
}
__device__ __forceinline__ unsigned short f2bf(float f){
  union { float f; unsigned int i; } v; v.f = f;
  unsigned int x = v.i;
  return (unsigned short)((x + 0x7fffu + ((x >> 16) & 1u)) >> 16); // RNE
}

// ---- prep: transpose to k8-major + atomic-free bucketing ------------------
// Wth[c][l]: slot s = k8*256 + n (k8 = k/8 in 0..31), 8 bf16 per slot (j=k%8).
//   Blocks 0..191: (mat = bid>>2, ck = bid&3), 64 k-rows each.
// Wt0[c]: slot = k8*256 + n, k8 0..3 (k padded 29->32). Blocks 192..199.
// Blocks 200..207: scatter sub-segment s = bid-200 (points [s*2048,(s+1)*2048))
//   into bucket[c*SEG + s*2048 + rank]; counts -> segcnt[s*8+c]. LDS atomics only.

__global__ __launch_bounds__(256) void prep_k(
    const float* __restrict__ Wh, const float* __restrict__ W0,
    const int* __restrict__ midx,
    unsigned short* __restrict__ Wth, unsigned short* __restrict__ Wt0,
    int* __restrict__ segcnt, int* __restrict__ bucket){
  int bid = blockIdx.x, tid = threadIdx.x;
  if (bid < 192){
    __shared__ __align__(16) unsigned short tile[64 * LSTR];
    int mat = bid >> 2, ck = bid & 3;
    const float* src = Wh + (size_t)mat * 65536 + (size_t)ck * 64 * 256;
    int r = tid >> 2, seg = (tid & 3) * 64;
    const float* sp = &src[r * 256 + seg];
    #pragma unroll
    for (int j8 = 0; j8 < 8; j8++){
      float4 f0 = *(const float4*)&sp[j8 * 8];
      float4 f1 = *(const float4*)&sp[j8 * 8 + 4];
      __align__(16) unsigned short t8[8];
      t8[0]=f2bf(f0.x); t8[1]=f2bf(f0.y); t8[2]=f2bf(f0.z); t8[3]=f2bf(f0.w);
      t8[4]=f2bf(f1.x); t8[5]=f2bf(f1.y); t8[6]=f2bf(f1.z); t8[7]=f2bf(f1.w);
      *(uint4*)&tile[r * LSTR + seg + j8 * 8] = *(const uint4*)t8;
    }
    __syncthreads();
    unsigned short* dst = Wth + (size_t)mat * 65536 + (size_t)ck * 16384;
    #pragma unroll
    for (int it = 0; it < 8; it++){
      int s = it * 256 + tid;
      int k8l = s >> 8, n = s & 255;
      __align__(16) unsigned short t8[8];
      #pragma unroll
      for (int j = 0; j < 8; j++) t8[j] = tile[(k8l * 8 + j) * LSTR + n];
      *(uint4*)&dst[(size_t)s * 8] = *(const uint4*)t8;
    }
  } else if (bid < 200){
    int c = bid - 192;
    #pragma unroll
    for (int it = 0; it < 4; it++){
      int s = it * 256 + tid;
      int k8 = s >> 8, n = s & 255;
      __align__(16) unsigned short t8[8];
      #pragma unroll
      for (int j = 0; j < 8; j++){
        int k = k8 * 8 + j;
        t8[j] = (k < 29) ? f2bf(W0[(c * 29 + k) * 256 + n]) : (unsigned short)0;
      }
      *(uint4*)&Wt0[(size_t)c * 8192 + (size_t)s * 8] = *(const uint4*)t8;
    }
  } else {
    __shared__ int cur[NCH];
    int sb = bid - 200;
    int lane = tid & 63;
    if (tid < NCH) cur[tid] = 0;
    __syncthreads();
    for (int it = 0; it < 8; it++){
      int i = sb * PSEG + it * 256 + tid;
      int c = midx[i];
      #pragma unroll
      for (int cc = 0; cc < NCH; cc++){
        unsigned long long m = __ballot(c == cc);
        if (!m) continue;
        int leader = (int)(__ffsll((long long)m) - 1);
        int wb = 0;
        if (lane == leader) wb = atomicAdd(&cur[cc], (int)__popcll(m));
        wb = __shfl(wb, leader);
        if (c == cc){
          int rk = (int)__popcll(m & ((1ull << lane) - 1));
          bucket[cc * SEG + sb * PSEG + wb + rk] = i;
        }
      }
    }
    __syncthreads();
    if (tid < NCH) segcnt[sb * NCH + tid] = cur[tid];
  }
}

// ---- main fused MLP: direct-to-VGPR full-layer B slab, k8-major loads -----

__global__ __launch_bounds__(256, 1) void mlp_k(
    const float* __restrict__ x,
    const float* __restrict__ proc,
    const float* __restrict__ b0,
    const float* __restrict__ bh,
    const float* __restrict__ Wl,
    const float* __restrict__ bl,
    const unsigned short* __restrict__ Wt0,
    const unsigned short* __restrict__ Wth,
    const int* __restrict__ segcnt,
    const int* __restrict__ bucket,
    float* __restrict__ out)
{
  __shared__ __align__(16) unsigned short actA[MT * LSTR];
  __shared__ __align__(16) unsigned short actB[MT * LSTR];
  __shared__ float biasb[7 * 256];
  __shared__ float wlb[512];
  __shared__ int ridx[MT];

  int chart = blockIdx.x & 7;     // XCD swizzle: chart c pinned to XCD c
  int tile  = blockIdx.x >> 3;

  // per-chart sub-segment prefix (8 entries)
  int pre[9];
  pre[0] = 0;
  #pragma unroll
  for (int s = 0; s < 8; s++) pre[s + 1] = pre[s] + segcnt[s * NCH + chart];
  int total = pre[8];
  int cnt = total - tile * MT;
  if (cnt <= 0) return;
  if (cnt > MT) cnt = MT;

  int tid  = threadIdx.x;
  int lane = tid & 63;
  int wv   = tid >> 6;
  int l15  = lane & 15;
  int quad = lane >> 4;
  int cb   = wv * 64;             // wave's output-column base

  // stage biases + Wl
  biasb[tid] = b0[chart * 256 + tid];
  #pragma unroll
  for (int j = 0; j < 6; j++)
    biasb[(j + 1) * 256 + tid] = bh[(chart * 6 + j) * 256 + tid];
  wlb[tid]       = Wl[chart * 512 + tid];
  wlb[256 + tid] = Wl[chart * 512 + 256 + tid];

  // positional encoding -> actA
  if (tid < MT){
    int row = tid;
    int g = -1;
    if (row < cnt){
      int r = tile * MT + row;
      int sb = 0, off = 0;
      #pragma unroll
      for (int s = 0; s < 8; s++)
        if (r >= pre[s]){ sb = s; off = r - pre[s]; }
      g = bucket[chart * SEG + sb * PSEG + off];
    }
    ridx[row] = g;
    unsigned short* rowp = &actA[row * LSTR];
    if (g >= 0){
      float xv0 = x[g*3+0], xv1 = x[g*3+1], xv2 = x[g*3+2];
      rowp[0] = f2bf(xv0); rowp[1] = f2bf(xv1); rowp[2] = f2bf(xv2);
      #pragma unroll
      for (int d = 1; d <= 4; d++){
        float s = (float)(1 << d) * 3.14159265358979323846f;
        int o = 3 + (d - 1) * 6;
        rowp[o+0] = f2bf(sinf(s*xv0)); rowp[o+1] = f2bf(sinf(s*xv1)); rowp[o+2] = f2bf(sinf(s*xv2));
        rowp[o+3] = f2bf(cosf(s*xv0)); rowp[o+4] = f2bf(cosf(s*xv1)); rowp[o+5] = f2bf(cosf(s*xv2));
      }
      rowp[27] = f2bf(proc[0]); rowp[28] = f2bf(proc[1]);
      rowp[29] = 0; rowp[30] = 0; rowp[31] = 0;
    } else {
      #pragma unroll
      for (int k = 0; k < 32; k++) rowp[k] = 0;
    }
  }
  __syncthreads();

  f32x4 acc[4][4];
  const f32x4 zz = {0.f, 0.f, 0.f, 0.f};

  // Layer 0: (64x32)@(32x256); B from Wt0 k8-major (k8 = quad)
  {
    const unsigned short* W0p = Wt0 + chart * 8192;
    bf16x8 b0r[4];
    #pragma unroll
    for (int nt = 0; nt < 4; nt++)
      b0r[nt] = *(const bf16x8*)&W0p[(size_t)(quad * 256 + cb + nt * 16 + l15) * 8];
    #pragma unroll
    for (int mt = 0; mt < 4; mt++){
      bf16x8 a0 = *(const bf16x8*)&actA[(mt * 16 + l15) * LSTR + quad * 8];
      #pragma unroll
      for (int nt = 0; nt < 4; nt++)
        acc[mt][nt] = __builtin_amdgcn_mfma_f32_16x16x32_bf16(a0, b0r[nt], zz, 0, 0, 0);
    }
    #pragma unroll
    for (int nt = 0; nt < 4; nt++){
      int col = cb + nt * 16 + l15;
      float bias = biasb[col];
      #pragma unroll
      for (int mt = 0; mt < 4; mt++)
        #pragma unroll
        for (int r = 0; r < 4; r++){
          float v = acc[mt][nt][r] + bias;
          v = v > 0.f ? v : 0.f;
          actB[(mt * 16 + quad * 4 + r) * LSTR + col] = f2bf(v);
        }
    }
  }
  __syncthreads();

  // 6 hidden layers: full-layer B slab (32 x 16B, k8-major contiguous) in VGPRs
  for (int l = 1; l <= 6; l++){
    const unsigned short* wl8 = Wth + ((size_t)(chart * 6 + l - 1) << 16);
    const unsigned short* ain = (l & 1) ? actB : actA;
    unsigned short* aout      = (l & 1) ? actA : actB;

    bf16x8 breg[8][4];
    #pragma unroll
    for (int kk = 0; kk < 8; kk++)
      #pragma unroll
      for (int nt = 0; nt < 4; nt++)
        breg[kk][nt] = *(const bf16x8*)
            &wl8[(size_t)((kk * 4 + quad) * 256 + cb + nt * 16 + l15) * 8];

    #pragma unroll
    for (int mt = 0; mt < 4; mt++){
      bf16x8 a[8];
      #pragma unroll
      for (int kk = 0; kk < 8; kk++)
        a[kk] = *(const bf16x8*)&ain[(mt * 16 + l15) * LSTR + kk * 32 + quad * 8];
      #pragma unroll
      for (int kk = 0; kk < 8; kk++)
        #pragma unroll
        for (int nt = 0; nt < 4; nt++)
          acc[mt][nt] = __builtin_amdgcn_mfma_f32_16x16x32_bf16(
              a[kk], breg[kk][nt], (kk == 0) ? zz : acc[mt][nt], 0, 0, 0);
    }

    #pragma unroll
    for (int nt = 0; nt < 4; nt++){
      int col = cb + nt * 16 + l15;
      float bias = biasb[l * 256 + col];
      #pragma unroll
      for (int mt = 0; mt < 4; mt++)
        #pragma unroll
        for (int r = 0; r < 4; r++){
          float v = acc[mt][nt][r] + bias;
          v = v > 0.f ? v : 0.f;
          aout[(mt * 16 + quad * 4 + r) * LSTR + col] = f2bf(v);
        }
    }
    __syncthreads();
  }

  // Final layer: (64x256)@(256x2) + sigmoid.
  // Ping-pong parity: L0->actB, L1->actA, L2->actB, L3->actA, L4->actB,
  // L5->actA, L6->actB  ==> layer-6 output is in actB (r9 bug: read actA).
  {
    int m = tid >> 2;
    int p = tid & 3;
    const unsigned short* hrow = actB + m * LSTR + p * 64;
    const float* wlp = wlb + p * 128;
    float s0 = 0.f, s1 = 0.f;
    #pragma unroll 8
    for (int k = 0; k < 64; k += 2){
      float4 w4 = *(const float4*)&wlp[k * 2];
      unsigned int h2 = *(const unsigned int*)&hrow[k];
      float hv0 = bf2f((unsigned short)(h2 & 0xffff));
      float hv1 = bf2f((unsigned short)(h2 >> 16));
      s0 += hv0 * w4.x + hv1 * w4.z;
      s1 += hv0 * w4.y + hv1 * w4.w;
    }
    s0 += __shfl_xor(s0, 1); s0 += __shfl_xor(s0, 2);
    s1 += __shfl_xor(s1, 1); s1 += __shfl_xor(s1, 2);
    if (p == 0){
      int g = ridx[m];
      if (g >= 0){
        float o0 = 1.f / (1.f + __expf(-(s0 + bl[chart*2+0])));
        float o1 = 1.f / (1.f + __expf(-(s1 + bl[chart*2+1])));
        *(float2*)&out[(size_t)g * 2] = make_float2(o0, o1);
      }
    }
  }
}

// ---- launch ---------------------------------------------------------------

extern "C" void kernel_launch(void* const* d_in, const int* in_sizes, int n_in,
                              void* d_out, int out_size, void* d_ws, size_t ws_size,
                              hipStream_t stream){
  const float* x    = (const float*)d_in[0];
  const float* proc = (const float*)d_in[1];
  const float* W0   = (const float*)d_in[2];
  const float* b0   = (const float*)d_in[3];
  const float* Wh   = (const float*)d_in[4];
  const float* bh   = (const float*)d_in[5];
  const float* Wl   = (const float*)d_in[6];
  const float* bl   = (const float*)d_in[7];
  const int* midx = (const int*)d_in[8];
  float* out = (float*)d_out;

  char* ws = (char*)d_ws;
  int* segcnt = (int*)ws;                           // 8 segs x 8 charts
  int* bucket = segcnt + 64;                        // NCH * SEG ints
  size_t off = (((size_t)(64 + NCH * SEG)) * 4 + 15) & ~(size_t)15;
  unsigned short* Wt0 = (unsigned short*)(ws + off);  // 8 * 8192 bf16
  unsigned short* Wth = Wt0 + NCH * 8192;             // 8 * 6 * 65536 bf16

  hipLaunchKernelGGL(prep_k, dim3(208),  dim3(256), 0, stream,
                     Wh, W0, midx, Wth, Wt0, segcnt, bucket);
  hipLaunchKernelGGL(mlp_k,  dim3(2048), dim3(256), 0, stream,
                     x, proc, b0, bh, Wl, bl, Wt0, Wth, segcnt, bucket, out);
}